// Round 1
// baseline (4612.932 us; speedup 1.0000x reference)
//
#include <hip/hip_runtime.h>
#include <math.h>

#define BATCH 16
#define CIN   512
#define MID   256
#define HW    4096
#define HEADS 8
#define CH    32
#define PI2   6.2831853071795864769f

// ------------------------------------------------------------------ K1: 1x1 reduce conv as GEMM
__global__ __launch_bounds__(256) void k_reduce(
    const float* __restrict__ x, const float* __restrict__ w,
    const float* __restrict__ bias, float* __restrict__ out)
{
  __shared__ float As[16][64];
  __shared__ float Bs[16][64];
  const int tid = threadIdx.x;
  const int n0 = blockIdx.x << 6;
  const int o0 = blockIdx.y << 6;
  const int b  = blockIdx.z;
  const int tc = tid & 15, tr = tid >> 4;
  const float* xb = x + (size_t)b * CIN * HW;
  float acc[4][4] = {{0.f}};
  for (int k0 = 0; k0 < CIN; k0 += 16) {
    for (int l = tid; l < 1024; l += 256) {
      int i = l >> 4, kk = l & 15;
      As[kk][i] = w[(size_t)(o0 + i) * CIN + (k0 + kk)];
    }
    for (int l = tid; l < 1024; l += 256) {
      int kk = l >> 6, j = l & 63;
      Bs[kk][j] = xb[(size_t)(k0 + kk) * HW + (n0 + j)];
    }
    __syncthreads();
    #pragma unroll
    for (int kk = 0; kk < 16; ++kk) {
      float a[4], bb[4];
      #pragma unroll
      for (int i = 0; i < 4; ++i) a[i] = As[kk][(tr << 2) + i];
      #pragma unroll
      for (int j = 0; j < 4; ++j) bb[j] = Bs[kk][(tc << 2) + j];
      #pragma unroll
      for (int i = 0; i < 4; ++i)
        #pragma unroll
        for (int j = 0; j < 4; ++j)
          acc[i][j] = fmaf(a[i], bb[j], acc[i][j]);
    }
    __syncthreads();
  }
  #pragma unroll
  for (int i = 0; i < 4; ++i) {
    int o = o0 + (tr << 2) + i;
    float bv = bias[o];
    size_t base = ((size_t)b * MID + o) * HW + n0 + (tc << 2);
    #pragma unroll
    for (int j = 0; j < 4; ++j) out[base + j] = acc[i][j] + bv;
  }
}

// ------------------------------------------------------------------ K2: depthwise 3x3 + BN + ReLU + spatial mean
__global__ __launch_bounds__(256) void k_dwbn(
    const float* __restrict__ in, const float* __restrict__ dww,
    const float* __restrict__ dwb, const float* __restrict__ gamma,
    const float* __restrict__ beta, const float* __restrict__ mean,
    const float* __restrict__ var, float* __restrict__ out,
    float* __restrict__ g0)
{
  __shared__ float pl[HW];
  __shared__ float red[256];
  const int p = blockIdx.x;
  const int c = p & (MID - 1);
  const int tid = threadIdx.x;
  const float* ip = in + (size_t)p * HW;
  for (int l = tid; l < HW; l += 256) pl[l] = ip[l];
  float wreg[9];
  #pragma unroll
  for (int i = 0; i < 9; ++i) wreg[i] = dww[c * 9 + i];
  const float bconv = dwb[c];
  const float inv = gamma[c] * rsqrtf(var[c] + 1e-5f);
  const float mu = mean[c], bt = beta[c];
  __syncthreads();
  float lsum = 0.f;
  float* op = out + (size_t)p * HW;
  for (int l = tid; l < HW; l += 256) {
    int y = l >> 6, xx0 = l & 63;
    float s = bconv;
    #pragma unroll
    for (int ky = 0; ky < 3; ++ky) {
      int yy = y + ky - 1;
      if (yy < 0 || yy >= 64) continue;
      #pragma unroll
      for (int kx = 0; kx < 3; ++kx) {
        int xx = xx0 + kx - 1;
        if (xx < 0 || xx >= 64) continue;
        s = fmaf(pl[(yy << 6) + xx], wreg[ky * 3 + kx], s);
      }
    }
    s = (s - mu) * inv + bt;
    s = fmaxf(s, 0.f);
    op[l] = s;
    lsum += s;
  }
  red[tid] = lsum;
  __syncthreads();
  for (int st = 128; st > 0; st >>= 1) {
    if (tid < st) red[tid] += red[tid + st];
    __syncthreads();
  }
  if (tid == 0) g0[p] = red[0] * (1.f / HW);
}

// ------------------------------------------------------------------ K3: SE gate MLP (tiny)
__global__ __launch_bounds__(256) void k_gate(
    const float* __restrict__ g0, const float* __restrict__ w1,
    const float* __restrict__ b1, const float* __restrict__ w2,
    const float* __restrict__ b2, float* __restrict__ g)
{
  __shared__ float gs[MID];
  __shared__ float hs[32];
  const int b = blockIdx.x;
  const int tid = threadIdx.x;
  gs[tid] = g0[b * MID + tid];
  __syncthreads();
  if (tid < 32) {
    float s = b1[tid];
    for (int c = 0; c < MID; ++c) s = fmaf(gs[c], w1[tid * MID + c], s);
    hs[tid] = fmaxf(s, 0.f);
  }
  __syncthreads();
  float s = b2[tid];
  #pragma unroll
  for (int j = 0; j < 32; ++j) s = fmaf(hs[j], w2[tid * 32 + j], s);
  g[b * MID + tid] = 1.f / (1.f + expf(-s));
}

// ------------------------------------------------------------------ K4: forward 2D DFT (ortho), real input -> complex out
__global__ __launch_bounds__(256) void k_fft_fwd(
    const float* __restrict__ in, float* __restrict__ outf)
{
  __shared__ float Ar[HW];
  __shared__ float Ai[HW];
  __shared__ float twc[64], tws[64];
  const int tid = threadIdx.x;
  const int p = blockIdx.x;
  if (tid < 64) {
    float ang = -PI2 * (float)tid * (1.f / 64.f);
    twc[tid] = cosf(ang);
    tws[tid] = sinf(ang);
  }
  const float* ip = in + (size_t)p * HW;
  for (int l = tid; l < HW; l += 256) Ar[l] = ip[l];
  __syncthreads();
  float orr[16], oii[16];
  #pragma unroll
  for (int ii = 0; ii < 16; ++ii) {
    int l = tid + (ii << 8);
    int r = l >> 6, k = l & 63;
    const float* row = Ar + (r << 6);
    float sr = 0.f, si = 0.f;
    for (int c = 0; c < 64; ++c) {
      int t = (c * k) & 63;
      float v = row[c];
      sr = fmaf(v, twc[t], sr);
      si = fmaf(v, tws[t], si);
    }
    orr[ii] = sr; oii[ii] = si;
  }
  __syncthreads();
  #pragma unroll
  for (int ii = 0; ii < 16; ++ii) {
    int l = tid + (ii << 8);
    Ar[l] = orr[ii]; Ai[l] = oii[ii];
  }
  __syncthreads();
  float2* op = (float2*)(outf + (size_t)p * (2 * HW));
  #pragma unroll
  for (int ii = 0; ii < 16; ++ii) {
    int l = tid + (ii << 8);
    int j = l >> 6, k = l & 63;
    float sr = 0.f, si = 0.f;
    for (int r = 0; r < 64; ++r) {
      int t = (r * j) & 63;
      float tc = twc[t], ts = tws[t];
      float ar = Ar[(r << 6) + k], ai = Ai[(r << 6) + k];
      sr += tc * ar - ts * ai;
      si += tc * ai + ts * ar;
    }
    op[l] = make_float2(sr * (1.f / 64.f), si * (1.f / 64.f));
  }
}

// ------------------------------------------------------------------ K5: FFT channel attention per (b,h)
__global__ __launch_bounds__(256) void k_attn(
    const float* __restrict__ fftf, const float* __restrict__ temp,
    float* __restrict__ outw)
{
  const int blk = blockIdx.x;
  const int b = blk >> 3, h = blk & 7;
  const float2* Q = (const float2*)fftf + ((size_t)b * MID + h * CH) * HW;
  __shared__ float Lr[32 * 65];
  __shared__ float Li[32 * 65];
  __shared__ float Ss[1024];
  __shared__ float Ns[32];
  __shared__ float P[1024];
  const int tid = threadIdx.x;
  const int c = tid >> 3, d0 = (tid & 7) << 2;
  float sacc[4] = {0.f, 0.f, 0.f, 0.f};
  float n2 = 0.f;
  for (int n0 = 0; n0 < HW; n0 += 64) {
    for (int l = tid; l < 2048; l += 256) {
      int r = l >> 6, nn = l & 63;
      float2 v = Q[(size_t)r * HW + n0 + nn];
      Lr[r * 65 + nn] = v.x;
      Li[r * 65 + nn] = v.y;
    }
    __syncthreads();
    const float* cr = Lr + c * 65;
    const float* ci = Li + c * 65;
    #pragma unroll
    for (int q = 0; q < 4; ++q) {
      const float* dr = Lr + (d0 + q) * 65;
      const float* di = Li + (d0 + q) * 65;
      float s = 0.f;
      for (int nn = 0; nn < 64; ++nn)
        s += cr[nn] * dr[nn] - ci[nn] * di[nn];
      sacc[q] += s;
    }
    if (tid < 32) {
      const float* rr = Lr + tid * 65;
      const float* ri = Li + tid * 65;
      float t = 0.f;
      for (int nn = 0; nn < 64; ++nn) t += rr[nn] * rr[nn] + ri[nn] * ri[nn];
      n2 += t;
    }
    __syncthreads();
  }
  #pragma unroll
  for (int q = 0; q < 4; ++q) Ss[(tid << 2) + q] = sacc[q];
  if (tid < 32) Ns[tid] = fmaxf(sqrtf(n2), 1e-12f);
  __syncthreads();
  if (tid < 32) {
    float tmp = temp[h];
    float nc = Ns[tid];
    float vals[32];
    float vmax = -1e30f;
    #pragma unroll
    for (int d = 0; d < 32; ++d) {
      float v = Ss[tid * 32 + d] / (nc * Ns[d]) * tmp;
      vals[d] = v;
      vmax = fmaxf(vmax, v);
    }
    float sum = 0.f;
    #pragma unroll
    for (int d = 0; d < 32; ++d) {
      float e = expf(vals[d] - vmax);
      vals[d] = e;
      sum += e;
    }
    float rinv = 1.f / sum;
    #pragma unroll
    for (int d = 0; d < 32; ++d) P[tid * 32 + d] = vals[d] * rinv;
  }
  __syncthreads();
  // phase B: out[c][n] = sum_d P[c][d] * Re(Q[d][n])
  const int cc = tid >> 3, nnb = (tid & 7) << 3;
  float* orow = outw + ((size_t)b * MID + h * CH) * HW;
  for (int n0 = 0; n0 < HW; n0 += 64) {
    for (int l = tid; l < 2048; l += 256) {
      int r = l >> 6, nn = l & 63;
      Lr[r * 65 + nn] = Q[(size_t)r * HW + n0 + nn].x;
    }
    __syncthreads();
    float o[8] = {0.f};
    const float* prow = P + cc * 32;
    #pragma unroll
    for (int d = 0; d < 32; ++d) {
      float pv = prow[d];
      const float* dr = Lr + d * 65 + nnb;
      #pragma unroll
      for (int i = 0; i < 8; ++i) o[i] = fmaf(pv, dr[i], o[i]);
    }
    #pragma unroll
    for (int i = 0; i < 8; ++i)
      orow[(size_t)cc * HW + n0 + nnb + i] = o[i];
    __syncthreads();
  }
}

// ------------------------------------------------------------------ K6: Re(fft2_ortho(real)) == Re(ifft2_ortho(real))
__global__ __launch_bounds__(256) void k_ifft_re(
    const float* __restrict__ in, float* __restrict__ out)
{
  __shared__ float Ar[HW];
  __shared__ float Ai[HW];
  __shared__ float twc[64], tws[64];
  const int tid = threadIdx.x;
  const int p = blockIdx.x;
  if (tid < 64) {
    float ang = -PI2 * (float)tid * (1.f / 64.f);
    twc[tid] = cosf(ang);
    tws[tid] = sinf(ang);
  }
  const float* ip = in + (size_t)p * HW;
  for (int l = tid; l < HW; l += 256) Ar[l] = ip[l];
  __syncthreads();
  float orr[16], oii[16];
  #pragma unroll
  for (int ii = 0; ii < 16; ++ii) {
    int l = tid + (ii << 8);
    int r = l >> 6, k = l & 63;
    const float* row = Ar + (r << 6);
    float sr = 0.f, si = 0.f;
    for (int c = 0; c < 64; ++c) {
      int t = (c * k) & 63;
      float v = row[c];
      sr = fmaf(v, twc[t], sr);
      si = fmaf(v, tws[t], si);
    }
    orr[ii] = sr; oii[ii] = si;
  }
  __syncthreads();
  #pragma unroll
  for (int ii = 0; ii < 16; ++ii) {
    int l = tid + (ii << 8);
    Ar[l] = orr[ii]; Ai[l] = oii[ii];
  }
  __syncthreads();
  float* op = out + (size_t)p * HW;
  #pragma unroll
  for (int ii = 0; ii < 16; ++ii) {
    int l = tid + (ii << 8);
    int j = l >> 6, k = l & 63;
    float sr = 0.f;
    for (int r = 0; r < 64; ++r) {
      int t = (r * j) & 63;
      sr += twc[t] * Ar[(r << 6) + k] - tws[t] * Ai[(r << 6) + k];
    }
    op[l] = sr * (1.f / 64.f);
  }
}

// ------------------------------------------------------------------ K7: fwm = (g/64) * Re(IDFT_unnorm(fft_feat^2)), in place over plane
__global__ __launch_bounds__(256) void k_fwm(
    float* __restrict__ fftf, const float* __restrict__ g)
{
  __shared__ float Zr[HW];
  __shared__ float Zi[HW];
  __shared__ float twc[64], tws[64];   // inverse twiddles (+sin)
  const int tid = threadIdx.x;
  const int p = blockIdx.x;
  if (tid < 64) {
    float ang = PI2 * (float)tid * (1.f / 64.f);
    twc[tid] = cosf(ang);
    tws[tid] = sinf(ang);
  }
  float* plane = fftf + (size_t)p * (2 * HW);
  const float2* F = (const float2*)plane;
  for (int l = tid; l < HW; l += 256) {
    float2 v = F[l];
    Zr[l] = v.x * v.x - v.y * v.y;
    Zi[l] = 2.f * v.x * v.y;
  }
  __syncthreads();
  float orr[16], oii[16];
  #pragma unroll
  for (int ii = 0; ii < 16; ++ii) {
    int l = tid + (ii << 8);
    int r = l >> 6, n = l & 63;
    const float* zr = Zr + (r << 6);
    const float* zi = Zi + (r << 6);
    float sr = 0.f, si = 0.f;
    for (int k = 0; k < 64; ++k) {
      int t = (k * n) & 63;
      float tc = twc[t], ts = tws[t];
      float ar = zr[k], ai = zi[k];
      sr += ar * tc - ai * ts;
      si += ar * ts + ai * tc;
    }
    orr[ii] = sr; oii[ii] = si;
  }
  __syncthreads();
  #pragma unroll
  for (int ii = 0; ii < 16; ++ii) {
    int l = tid + (ii << 8);
    Zr[l] = orr[ii]; Zi[l] = oii[ii];
  }
  __syncthreads();
  const float gg = g[p] * (1.f / 64.f);
  #pragma unroll
  for (int ii = 0; ii < 16; ++ii) {
    int l = tid + (ii << 8);
    int m = l >> 6, n = l & 63;
    float sr = 0.f;
    for (int j = 0; j < 64; ++j) {
      int t = (j * m) & 63;
      sr += twc[t] * Zr[(j << 6) + n] - tws[t] * Zi[(j << 6) + n];
    }
    plane[l] = sr * gg;   // writes only first half of plane; all reads done pre-barrier
  }
}

// ------------------------------------------------------------------ K8: post GEMM over concat [out_sp, fwm] + bias + residual
__global__ __launch_bounds__(256) void k_post(
    const float* __restrict__ outsp, const float* __restrict__ fwmbuf,
    const float* __restrict__ w, const float* __restrict__ bias,
    const float* __restrict__ x, float* __restrict__ y)
{
  __shared__ float As[16][64];
  __shared__ float Bs[16][64];
  const int tid = threadIdx.x;
  const int n0 = blockIdx.x << 6;
  const int o0 = blockIdx.y << 6;
  const int b  = blockIdx.z;
  const int tc = tid & 15, tr = tid >> 4;
  float acc[4][4] = {{0.f}};
  for (int k0 = 0; k0 < 2 * MID; k0 += 16) {
    for (int l = tid; l < 1024; l += 256) {
      int i = l >> 4, kk = l & 15;
      As[kk][i] = w[(size_t)(o0 + i) * (2 * MID) + (k0 + kk)];
    }
    for (int l = tid; l < 1024; l += 256) {
      int kk = l >> 6, j = l & 63;
      int cidx = k0 + kk;
      const float* src = (cidx < MID)
          ? outsp + ((size_t)b * MID + cidx) * HW
          : fwmbuf + ((size_t)b * MID + (cidx - MID)) * (2 * HW);
      Bs[kk][j] = src[n0 + j];
    }
    __syncthreads();
    #pragma unroll
    for (int kk = 0; kk < 16; ++kk) {
      float a[4], bb[4];
      #pragma unroll
      for (int i = 0; i < 4; ++i) a[i] = As[kk][(tr << 2) + i];
      #pragma unroll
      for (int j = 0; j < 4; ++j) bb[j] = Bs[kk][(tc << 2) + j];
      #pragma unroll
      for (int i = 0; i < 4; ++i)
        #pragma unroll
        for (int j = 0; j < 4; ++j)
          acc[i][j] = fmaf(a[i], bb[j], acc[i][j]);
    }
    __syncthreads();
  }
  #pragma unroll
  for (int i = 0; i < 4; ++i) {
    int o = o0 + (tr << 2) + i;
    float bv = bias[o];
    size_t base = ((size_t)b * CIN + o) * HW + n0 + (tc << 2);
    #pragma unroll
    for (int j = 0; j < 4; ++j) y[base + j] = acc[i][j] + bv + x[base + j];
  }
}

// ------------------------------------------------------------------ launch
extern "C" void kernel_launch(void* const* d_in, const int* in_sizes, int n_in,
                              void* d_out, int out_size, void* d_ws, size_t ws_size,
                              hipStream_t stream)
{
  const float* x    = (const float*)d_in[0];
  const float* rw   = (const float*)d_in[1];
  const float* rb   = (const float*)d_in[2];
  const float* dww  = (const float*)d_in[3];
  const float* dwb  = (const float*)d_in[4];
  const float* bng  = (const float*)d_in[5];
  const float* bnb  = (const float*)d_in[6];
  const float* bnm  = (const float*)d_in[7];
  const float* bnv  = (const float*)d_in[8];
  const float* gw1  = (const float*)d_in[9];
  const float* gb1  = (const float*)d_in[10];
  const float* gw2  = (const float*)d_in[11];
  const float* gb2  = (const float*)d_in[12];
  const float* temp = (const float*)d_in[13];
  const float* pw   = (const float*)d_in[14];
  const float* pb   = (const float*)d_in[15];
  float* y = (float*)d_out;

  float* ws = (float*)d_ws;
  const size_t PL = (size_t)BATCH * MID * HW;   // 16,777,216 floats
  float* xr   = ws;                 // xr, later out_sp
  float* fftf = ws + PL;            // 2*PL floats (complex), fwm overwrites plane heads
  float* g0   = ws + 3 * PL;        // [B*MID]
  float* gg   = g0 + BATCH * MID;   // [B*MID]
  float* xr0  = y;                  // first half of d_out: xr0, later attn_out

  k_reduce <<<dim3(64, 4, BATCH),   256, 0, stream>>>(x, rw, rb, xr0);
  k_dwbn   <<<dim3(BATCH * MID),    256, 0, stream>>>(xr0, dww, dwb, bng, bnb, bnm, bnv, xr, g0);
  k_gate   <<<dim3(BATCH),          256, 0, stream>>>(g0, gw1, gb1, gw2, gb2, gg);
  k_fft_fwd<<<dim3(BATCH * MID),    256, 0, stream>>>(xr, fftf);
  k_attn   <<<dim3(BATCH * HEADS),  256, 0, stream>>>(fftf, temp, xr0);
  k_ifft_re<<<dim3(BATCH * MID),    256, 0, stream>>>(xr0, xr);
  k_fwm    <<<dim3(BATCH * MID),    256, 0, stream>>>(fftf, gg);
  k_post   <<<dim3(64, 8, BATCH),   256, 0, stream>>>(xr, fftf, pw, pb, x, y);
}

// Round 2
// 2687.361 us; speedup vs baseline: 1.7165x; 1.7165x over previous
//
#include <hip/hip_runtime.h>
#include <math.h>

#define BATCH 16
#define CIN   512
#define MID   256
#define HW    4096
#define HEADS 8
#define CH    32
#define PI2   6.2831853071795864769f

// ------------------------------------------------------------------ K1: 1x1 reduce conv as GEMM
__global__ __launch_bounds__(256) void k_reduce(
    const float* __restrict__ x, const float* __restrict__ w,
    const float* __restrict__ bias, float* __restrict__ out)
{
  __shared__ float As[16][64];
  __shared__ float Bs[16][64];
  const int tid = threadIdx.x;
  const int n0 = blockIdx.x << 6;
  const int o0 = blockIdx.y << 6;
  const int b  = blockIdx.z;
  const int tc = tid & 15, tr = tid >> 4;
  const float* xb = x + (size_t)b * CIN * HW;
  float acc[4][4] = {{0.f}};
  for (int k0 = 0; k0 < CIN; k0 += 16) {
    for (int l = tid; l < 1024; l += 256) {
      int i = l >> 4, kk = l & 15;
      As[kk][i] = w[(size_t)(o0 + i) * CIN + (k0 + kk)];
    }
    for (int l = tid; l < 1024; l += 256) {
      int kk = l >> 6, j = l & 63;
      Bs[kk][j] = xb[(size_t)(k0 + kk) * HW + (n0 + j)];
    }
    __syncthreads();
    #pragma unroll
    for (int kk = 0; kk < 16; ++kk) {
      float a[4], bb[4];
      #pragma unroll
      for (int i = 0; i < 4; ++i) a[i] = As[kk][(tr << 2) + i];
      #pragma unroll
      for (int j = 0; j < 4; ++j) bb[j] = Bs[kk][(tc << 2) + j];
      #pragma unroll
      for (int i = 0; i < 4; ++i)
        #pragma unroll
        for (int j = 0; j < 4; ++j)
          acc[i][j] = fmaf(a[i], bb[j], acc[i][j]);
    }
    __syncthreads();
  }
  #pragma unroll
  for (int i = 0; i < 4; ++i) {
    int o = o0 + (tr << 2) + i;
    float bv = bias[o];
    size_t base = ((size_t)b * MID + o) * HW + n0 + (tc << 2);
    #pragma unroll
    for (int j = 0; j < 4; ++j) out[base + j] = acc[i][j] + bv;
  }
}

// ------------------------------------------------------------------ K2: depthwise 3x3 + BN + ReLU + spatial mean
__global__ __launch_bounds__(256) void k_dwbn(
    const float* __restrict__ in, const float* __restrict__ dww,
    const float* __restrict__ dwb, const float* __restrict__ gamma,
    const float* __restrict__ beta, const float* __restrict__ mean,
    const float* __restrict__ var, float* __restrict__ out,
    float* __restrict__ g0)
{
  __shared__ float pl[HW];
  __shared__ float red[256];
  const int p = blockIdx.x;
  const int c = p & (MID - 1);
  const int tid = threadIdx.x;
  const float* ip = in + (size_t)p * HW;
  for (int l = tid; l < HW; l += 256) pl[l] = ip[l];
  float wreg[9];
  #pragma unroll
  for (int i = 0; i < 9; ++i) wreg[i] = dww[c * 9 + i];
  const float bconv = dwb[c];
  const float inv = gamma[c] * rsqrtf(var[c] + 1e-5f);
  const float mu = mean[c], bt = beta[c];
  __syncthreads();
  float lsum = 0.f;
  float* op = out + (size_t)p * HW;
  for (int l = tid; l < HW; l += 256) {
    int y = l >> 6, xx0 = l & 63;
    float s = bconv;
    #pragma unroll
    for (int ky = 0; ky < 3; ++ky) {
      int yy = y + ky - 1;
      if (yy < 0 || yy >= 64) continue;
      #pragma unroll
      for (int kx = 0; kx < 3; ++kx) {
        int xx = xx0 + kx - 1;
        if (xx < 0 || xx >= 64) continue;
        s = fmaf(pl[(yy << 6) + xx], wreg[ky * 3 + kx], s);
      }
    }
    s = (s - mu) * inv + bt;
    s = fmaxf(s, 0.f);
    op[l] = s;
    lsum += s;
  }
  red[tid] = lsum;
  __syncthreads();
  for (int st = 128; st > 0; st >>= 1) {
    if (tid < st) red[tid] += red[tid + st];
    __syncthreads();
  }
  if (tid == 0) g0[p] = red[0] * (1.f / HW);
}

// ------------------------------------------------------------------ K3: SE gate MLP (tiny)
__global__ __launch_bounds__(256) void k_gate(
    const float* __restrict__ g0, const float* __restrict__ w1,
    const float* __restrict__ b1, const float* __restrict__ w2,
    const float* __restrict__ b2, float* __restrict__ g)
{
  __shared__ float gs[MID];
  __shared__ float hs[32];
  const int b = blockIdx.x;
  const int tid = threadIdx.x;
  gs[tid] = g0[b * MID + tid];
  __syncthreads();
  if (tid < 32) {
    float s = b1[tid];
    for (int c = 0; c < MID; ++c) s = fmaf(gs[c], w1[tid * MID + c], s);
    hs[tid] = fmaxf(s, 0.f);
  }
  __syncthreads();
  float s = b2[tid];
  #pragma unroll
  for (int j = 0; j < 32; ++j) s = fmaf(hs[j], w2[tid * 32 + j], s);
  g[b * MID + tid] = 1.f / (1.f + expf(-s));
}

// ------------------------------------------------------------------ K4: forward 2D DFT (ortho), real input -> complex out
__global__ __launch_bounds__(256) void k_fft_fwd(
    const float* __restrict__ in, float* __restrict__ outf)
{
  __shared__ float Ar[HW];
  __shared__ float Ai[HW];
  __shared__ float twc[64], tws[64];
  const int tid = threadIdx.x;
  const int p = blockIdx.x;
  if (tid < 64) {
    float ang = -PI2 * (float)tid * (1.f / 64.f);
    twc[tid] = cosf(ang);
    tws[tid] = sinf(ang);
  }
  const float* ip = in + (size_t)p * HW;
  for (int l = tid; l < HW; l += 256) Ar[l] = ip[l];
  __syncthreads();
  float orr[16], oii[16];
  #pragma unroll
  for (int ii = 0; ii < 16; ++ii) {
    int l = tid + (ii << 8);
    int r = l >> 6, k = l & 63;
    const float* row = Ar + (r << 6);
    float sr = 0.f, si = 0.f;
    for (int c = 0; c < 64; ++c) {
      int t = (c * k) & 63;
      float v = row[c];
      sr = fmaf(v, twc[t], sr);
      si = fmaf(v, tws[t], si);
    }
    orr[ii] = sr; oii[ii] = si;
  }
  __syncthreads();
  #pragma unroll
  for (int ii = 0; ii < 16; ++ii) {
    int l = tid + (ii << 8);
    Ar[l] = orr[ii]; Ai[l] = oii[ii];
  }
  __syncthreads();
  float2* op = (float2*)(outf + (size_t)p * (2 * HW));
  #pragma unroll
  for (int ii = 0; ii < 16; ++ii) {
    int l = tid + (ii << 8);
    int j = l >> 6, k = l & 63;
    float sr = 0.f, si = 0.f;
    for (int r = 0; r < 64; ++r) {
      int t = (r * j) & 63;
      float tc = twc[t], ts = tws[t];
      float ar = Ar[(r << 6) + k], ai = Ai[(r << 6) + k];
      sr += tc * ar - ts * ai;
      si += tc * ai + ts * ar;
    }
    op[l] = make_float2(sr * (1.f / 64.f), si * (1.f / 64.f));
  }
}

// ------------------------------------------------------------------ K5a: attention scores, partial over n-chunks
// S[bh,c,d] += sum_n (qr_c qr_d - qi_c qi_d) ; N2[bh,c] += sum_n |q_c|^2
__global__ __launch_bounds__(256) void k_attn_s(
    const float* __restrict__ fftf, float* __restrict__ Sbuf,
    float* __restrict__ Nbuf)
{
  const int bh = blockIdx.y;
  const int n0 = blockIdx.x << 8;             // 256 cols / chunk
  const int b = bh >> 3, h = bh & 7;
  const float2* Q = (const float2*)fftf + ((size_t)b * MID + (size_t)h * CH) * HW;
  __shared__ float2 Lri[32 * 257];            // interleaved (r,i), stride 257 float2
  const int tid = threadIdx.x;
  for (int l = tid; l < 8192; l += 256) {
    int r = l >> 8, nn = l & 255;
    Lri[r * 257 + nn] = Q[(size_t)r * HW + n0 + nn];
  }
  __syncthreads();
  const int c0 = (tid >> 4) << 1;             // 2x2 register tile of S
  const int d0 = (tid & 15) << 1;
  const float2* ca = Lri + c0 * 257;
  const float2* cb = ca + 257;
  const float2* da = Lri + d0 * 257;
  const float2* db = da + 257;
  float s00 = 0.f, s01 = 0.f, s10 = 0.f, s11 = 0.f;
  for (int nn = 0; nn < 256; ++nn) {
    float2 A0 = ca[nn], A1 = cb[nn], B0 = da[nn], B1 = db[nn];
    s00 = fmaf(A0.x, B0.x, s00); s00 = fmaf(-A0.y, B0.y, s00);
    s01 = fmaf(A0.x, B1.x, s01); s01 = fmaf(-A0.y, B1.y, s01);
    s10 = fmaf(A1.x, B0.x, s10); s10 = fmaf(-A1.y, B0.y, s10);
    s11 = fmaf(A1.x, B1.x, s11); s11 = fmaf(-A1.y, B1.y, s11);
  }
  float* Sp = Sbuf + (size_t)bh * 1024;
  atomicAdd(&Sp[(c0    ) * 32 + d0    ], s00);
  atomicAdd(&Sp[(c0    ) * 32 + d0 + 1], s01);
  atomicAdd(&Sp[(c0 + 1) * 32 + d0    ], s10);
  atomicAdd(&Sp[(c0 + 1) * 32 + d0 + 1], s11);
  // row norms: 8 threads per row, stride-8 columns
  {
    int r = tid >> 3;
    const float2* rr = Lri + r * 257;
    float t = 0.f;
    for (int nn = tid & 7; nn < 256; nn += 8) {
      float2 v = rr[nn];
      t = fmaf(v.x, v.x, t);
      t = fmaf(v.y, v.y, t);
    }
    atomicAdd(&Nbuf[bh * 32 + r], t);
  }
}

// ------------------------------------------------------------------ K5b: normalize + temperature + softmax (in place on Sbuf)
__global__ __launch_bounds__(64) void k_attn_sm(
    float* __restrict__ Sbuf, const float* __restrict__ Nbuf,
    const float* __restrict__ temp)
{
  const int bh = blockIdx.x;
  const int h = bh & 7;
  const int tid = threadIdx.x;
  if (tid < 32) {
    float nc = fmaxf(sqrtf(Nbuf[bh * 32 + tid]), 1e-12f);
    float tmp = temp[h];
    float* Sp = Sbuf + (size_t)bh * 1024 + tid * 32;
    float vals[32];
    float vmax = -1e30f;
    #pragma unroll
    for (int d = 0; d < 32; ++d) {
      float nd = fmaxf(sqrtf(Nbuf[bh * 32 + d]), 1e-12f);
      float v = Sp[d] / (nc * nd) * tmp;
      vals[d] = v;
      vmax = fmaxf(vmax, v);
    }
    float sum = 0.f;
    #pragma unroll
    for (int d = 0; d < 32; ++d) {
      float e = expf(vals[d] - vmax);
      vals[d] = e;
      sum += e;
    }
    float rinv = 1.f / sum;
    #pragma unroll
    for (int d = 0; d < 32; ++d) Sp[d] = vals[d] * rinv;
  }
}

// ------------------------------------------------------------------ K5c: out[c,n] = sum_d P[c,d] * Re(Q[d,n])
__global__ __launch_bounds__(256) void k_attn_o(
    const float* __restrict__ fftf, const float* __restrict__ Sbuf,
    float* __restrict__ outw)
{
  const int bh = blockIdx.y;
  const int n0 = blockIdx.x << 9;             // 512 cols / chunk
  const int b = bh >> 3, h = bh & 7;
  const float2* Q = (const float2*)fftf + ((size_t)b * MID + (size_t)h * CH) * HW;
  __shared__ float P[1024];
  __shared__ float Lr[32 * 514];              // 32 rows x 512 cols (+2 pad), real part
  const int tid = threadIdx.x;
  for (int l = tid; l < 1024; l += 256) P[l] = Sbuf[(size_t)bh * 1024 + l];
  for (int l = tid; l < 32 * 512; l += 256) {
    int r = l >> 9, nn = l & 511;
    Lr[r * 514 + nn] = Q[(size_t)r * HW + n0 + nn].x;
  }
  __syncthreads();
  const float2* Lr2 = (const float2*)Lr;      // stride 257 float2 per row
  const float4* P4 = (const float4*)P;
  float* orow = outw + ((size_t)b * MID + (size_t)h * CH) * HW + n0;
  #pragma unroll 4
  for (int c = 0; c < 32; ++c) {
    float s0 = 0.f, s1 = 0.f;
    #pragma unroll
    for (int j = 0; j < 8; ++j) {
      float4 pv = P4[c * 8 + j];
      int d = j << 2;
      float2 v0 = Lr2[(d + 0) * 257 + tid];
      float2 v1 = Lr2[(d + 1) * 257 + tid];
      float2 v2 = Lr2[(d + 2) * 257 + tid];
      float2 v3 = Lr2[(d + 3) * 257 + tid];
      s0 = fmaf(pv.x, v0.x, s0); s1 = fmaf(pv.x, v0.y, s1);
      s0 = fmaf(pv.y, v1.x, s0); s1 = fmaf(pv.y, v1.y, s1);
      s0 = fmaf(pv.z, v2.x, s0); s1 = fmaf(pv.z, v2.y, s1);
      s0 = fmaf(pv.w, v3.x, s0); s1 = fmaf(pv.w, v3.y, s1);
    }
    ((float2*)(orow + (size_t)c * HW))[tid] = make_float2(s0, s1);
  }
}

// ------------------------------------------------------------------ K6: Re(fft2_ortho(real)) == Re(ifft2_ortho(real))
__global__ __launch_bounds__(256) void k_ifft_re(
    const float* __restrict__ in, float* __restrict__ out)
{
  __shared__ float Ar[HW];
  __shared__ float Ai[HW];
  __shared__ float twc[64], tws[64];
  const int tid = threadIdx.x;
  const int p = blockIdx.x;
  if (tid < 64) {
    float ang = -PI2 * (float)tid * (1.f / 64.f);
    twc[tid] = cosf(ang);
    tws[tid] = sinf(ang);
  }
  const float* ip = in + (size_t)p * HW;
  for (int l = tid; l < HW; l += 256) Ar[l] = ip[l];
  __syncthreads();
  float orr[16], oii[16];
  #pragma unroll
  for (int ii = 0; ii < 16; ++ii) {
    int l = tid + (ii << 8);
    int r = l >> 6, k = l & 63;
    const float* row = Ar + (r << 6);
    float sr = 0.f, si = 0.f;
    for (int c = 0; c < 64; ++c) {
      int t = (c * k) & 63;
      float v = row[c];
      sr = fmaf(v, twc[t], sr);
      si = fmaf(v, tws[t], si);
    }
    orr[ii] = sr; oii[ii] = si;
  }
  __syncthreads();
  #pragma unroll
  for (int ii = 0; ii < 16; ++ii) {
    int l = tid + (ii << 8);
    Ar[l] = orr[ii]; Ai[l] = oii[ii];
  }
  __syncthreads();
  float* op = out + (size_t)p * HW;
  #pragma unroll
  for (int ii = 0; ii < 16; ++ii) {
    int l = tid + (ii << 8);
    int j = l >> 6, k = l & 63;
    float sr = 0.f;
    for (int r = 0; r < 64; ++r) {
      int t = (r * j) & 63;
      sr += twc[t] * Ar[(r << 6) + k] - tws[t] * Ai[(r << 6) + k];
    }
    op[l] = sr * (1.f / 64.f);
  }
}

// ------------------------------------------------------------------ K7: fwm = (g/64) * Re(IDFT_unnorm(fft_feat^2)), in place over plane
__global__ __launch_bounds__(256) void k_fwm(
    float* __restrict__ fftf, const float* __restrict__ g)
{
  __shared__ float Zr[HW];
  __shared__ float Zi[HW];
  __shared__ float twc[64], tws[64];   // inverse twiddles (+sin)
  const int tid = threadIdx.x;
  const int p = blockIdx.x;
  if (tid < 64) {
    float ang = PI2 * (float)tid * (1.f / 64.f);
    twc[tid] = cosf(ang);
    tws[tid] = sinf(ang);
  }
  float* plane = fftf + (size_t)p * (2 * HW);
  const float2* F = (const float2*)plane;
  for (int l = tid; l < HW; l += 256) {
    float2 v = F[l];
    Zr[l] = v.x * v.x - v.y * v.y;
    Zi[l] = 2.f * v.x * v.y;
  }
  __syncthreads();
  float orr[16], oii[16];
  #pragma unroll
  for (int ii = 0; ii < 16; ++ii) {
    int l = tid + (ii << 8);
    int r = l >> 6, n = l & 63;
    const float* zr = Zr + (r << 6);
    const float* zi = Zi + (r << 6);
    float sr = 0.f, si = 0.f;
    for (int k = 0; k < 64; ++k) {
      int t = (k * n) & 63;
      float tc = twc[t], ts = tws[t];
      float ar = zr[k], ai = zi[k];
      sr += ar * tc - ai * ts;
      si += ar * ts + ai * tc;
    }
    orr[ii] = sr; oii[ii] = si;
  }
  __syncthreads();
  #pragma unroll
  for (int ii = 0; ii < 16; ++ii) {
    int l = tid + (ii << 8);
    Zr[l] = orr[ii]; Zi[l] = oii[ii];
  }
  __syncthreads();
  const float gg = g[p] * (1.f / 64.f);
  #pragma unroll
  for (int ii = 0; ii < 16; ++ii) {
    int l = tid + (ii << 8);
    int m = l >> 6, n = l & 63;
    float sr = 0.f;
    for (int j = 0; j < 64; ++j) {
      int t = (j * m) & 63;
      sr += twc[t] * Zr[(j << 6) + n] - tws[t] * Zi[(j << 6) + n];
    }
    plane[l] = sr * gg;   // writes only first half of plane; all reads done pre-barrier
  }
}

// ------------------------------------------------------------------ K8: post GEMM over concat [out_sp, fwm] + bias + residual
__global__ __launch_bounds__(256) void k_post(
    const float* __restrict__ outsp, const float* __restrict__ fwmbuf,
    const float* __restrict__ w, const float* __restrict__ bias,
    const float* __restrict__ x, float* __restrict__ y)
{
  __shared__ float As[16][64];
  __shared__ float Bs[16][64];
  const int tid = threadIdx.x;
  const int n0 = blockIdx.x << 6;
  const int o0 = blockIdx.y << 6;
  const int b  = blockIdx.z;
  const int tc = tid & 15, tr = tid >> 4;
  float acc[4][4] = {{0.f}};
  for (int k0 = 0; k0 < 2 * MID; k0 += 16) {
    for (int l = tid; l < 1024; l += 256) {
      int i = l >> 4, kk = l & 15;
      As[kk][i] = w[(size_t)(o0 + i) * (2 * MID) + (k0 + kk)];
    }
    for (int l = tid; l < 1024; l += 256) {
      int kk = l >> 6, j = l & 63;
      int cidx = k0 + kk;
      const float* src = (cidx < MID)
          ? outsp + ((size_t)b * MID + cidx) * HW
          : fwmbuf + ((size_t)b * MID + (cidx - MID)) * (2 * HW);
      Bs[kk][j] = src[n0 + j];
    }
    __syncthreads();
    #pragma unroll
    for (int kk = 0; kk < 16; ++kk) {
      float a[4], bb[4];
      #pragma unroll
      for (int i = 0; i < 4; ++i) a[i] = As[kk][(tr << 2) + i];
      #pragma unroll
      for (int j = 0; j < 4; ++j) bb[j] = Bs[kk][(tc << 2) + j];
      #pragma unroll
      for (int i = 0; i < 4; ++i)
        #pragma unroll
        for (int j = 0; j < 4; ++j)
          acc[i][j] = fmaf(a[i], bb[j], acc[i][j]);
    }
    __syncthreads();
  }
  #pragma unroll
  for (int i = 0; i < 4; ++i) {
    int o = o0 + (tr << 2) + i;
    float bv = bias[o];
    size_t base = ((size_t)b * CIN + o) * HW + n0 + (tc << 2);
    #pragma unroll
    for (int j = 0; j < 4; ++j) y[base + j] = acc[i][j] + bv + x[base + j];
  }
}

// ------------------------------------------------------------------ launch
extern "C" void kernel_launch(void* const* d_in, const int* in_sizes, int n_in,
                              void* d_out, int out_size, void* d_ws, size_t ws_size,
                              hipStream_t stream)
{
  const float* x    = (const float*)d_in[0];
  const float* rw   = (const float*)d_in[1];
  const float* rb   = (const float*)d_in[2];
  const float* dww  = (const float*)d_in[3];
  const float* dwb  = (const float*)d_in[4];
  const float* bng  = (const float*)d_in[5];
  const float* bnb  = (const float*)d_in[6];
  const float* bnm  = (const float*)d_in[7];
  const float* bnv  = (const float*)d_in[8];
  const float* gw1  = (const float*)d_in[9];
  const float* gb1  = (const float*)d_in[10];
  const float* gw2  = (const float*)d_in[11];
  const float* gb2  = (const float*)d_in[12];
  const float* temp = (const float*)d_in[13];
  const float* pw   = (const float*)d_in[14];
  const float* pb   = (const float*)d_in[15];
  float* y = (float*)d_out;

  float* ws = (float*)d_ws;
  const size_t PL = (size_t)BATCH * MID * HW;   // 16,777,216 floats
  float* xr   = ws;                 // xr, later out_sp
  float* fftf = ws + PL;            // 2*PL floats (complex), fwm overwrites plane heads
  float* g0   = ws + 3 * PL;        // [B*MID]
  float* gg   = g0 + BATCH * MID;   // [B*MID]
  float* Sbuf = gg + BATCH * MID;   // [128*1024] attention scores / probs
  float* Nbuf = Sbuf + BATCH * HEADS * 1024;  // [128*32] row norms^2
  float* xr0  = y;                  // first half of d_out: xr0, later attn_out

  hipMemsetAsync(Sbuf, 0, (size_t)(BATCH * HEADS * (1024 + 32)) * sizeof(float), stream);

  k_reduce <<<dim3(64, 4, BATCH),   256, 0, stream>>>(x, rw, rb, xr0);
  k_dwbn   <<<dim3(BATCH * MID),    256, 0, stream>>>(xr0, dww, dwb, bng, bnb, bnm, bnv, xr, g0);
  k_gate   <<<dim3(BATCH),          256, 0, stream>>>(g0, gw1, gb1, gw2, gb2, gg);
  k_fft_fwd<<<dim3(BATCH * MID),    256, 0, stream>>>(xr, fftf);
  k_attn_s <<<dim3(16, BATCH * HEADS), 256, 0, stream>>>(fftf, Sbuf, Nbuf);
  k_attn_sm<<<dim3(BATCH * HEADS),  64,  0, stream>>>(Sbuf, Nbuf, temp);
  k_attn_o <<<dim3(8, BATCH * HEADS), 256, 0, stream>>>(fftf, Sbuf, xr0);
  k_ifft_re<<<dim3(BATCH * MID),    256, 0, stream>>>(xr0, xr);
  k_fwm    <<<dim3(BATCH * MID),    256, 0, stream>>>(fftf, gg);
  k_post   <<<dim3(64, 8, BATCH),   256, 0, stream>>>(xr, fftf, pw, pb, x, y);
}

// Round 3
// 1833.432 us; speedup vs baseline: 2.5160x; 1.4658x over previous
//
#include <hip/hip_runtime.h>
#include <math.h>

#define BATCH 16
#define CIN   512
#define MID   256
#define HW    4096
#define HEADS 8
#define CH    32
#define PI2   6.2831853071795864769f

typedef __attribute__((ext_vector_type(8))) short short8;
typedef __attribute__((ext_vector_type(4))) float floatx4;

__device__ inline unsigned short f2b(float f) {
  union { float f; unsigned int u; } v; v.f = f;
  unsigned int u = v.u;
  unsigned int r = (u + 0x7fffu + ((u >> 16) & 1u)) >> 16;
  return (unsigned short)r;
}

// ------------------------------------------------------------------ K0: cast weights to bf16
__global__ __launch_bounds__(256) void k_castw(
    const float* __restrict__ rw, const float* __restrict__ pw,
    unsigned short* __restrict__ rwB, unsigned short* __restrict__ pwB)
{
  int i = blockIdx.x * 256 + threadIdx.x;
  if (i < MID * CIN) rwB[i] = f2b(rw[i]);
  if (i < CIN * 2 * MID) pwB[i] = f2b(pw[i]);
}

// ------------------------------------------------------------------ MFMA GEMM: C[M x N] = A[M x K=512 bf16] * B[K x N] (+bias)(+resid)
// tile 128x128, 4 waves, each wave 64x64 via 4x4 mfma_f32_16x16x32_bf16
#define LDT 40   // LDS row stride (bf16 elems); 80B keeps b128 16B-aligned

// variant 1: B = fp32 global (x), converted during staging
__global__ __launch_bounds__(256) void k_gemm_red(
    const unsigned short* __restrict__ A, const float* __restrict__ Bg0,
    const float* __restrict__ bias, float* __restrict__ out)
{
  __shared__ __align__(16) short As[128 * LDT];
  __shared__ __align__(16) short Bs[128 * LDT];
  const int tid = threadIdx.x;
  const int n0 = blockIdx.x << 7;
  const int m0 = blockIdx.y << 7;
  const int b  = blockIdx.z;
  const int lane = tid & 63, wave = tid >> 6;
  const int wm = (wave >> 1) << 6, wn = (wave & 1) << 6;
  const int l16 = lane & 15, quad = lane >> 4;
  const float* Bg = Bg0 + (size_t)b * CIN * HW;
  floatx4 acc[4][4] = {};
  for (int k0 = 0; k0 < CIN; k0 += 32) {
    #pragma unroll
    for (int l = tid; l < 512; l += 256) {
      int m = l >> 2, ko = (l & 3) << 3;
      *(uint4*)&As[m * LDT + ko] = *(const uint4*)&A[(size_t)(m0 + m) * CIN + k0 + ko];
    }
    #pragma unroll
    for (int it = 0; it < 16; ++it) {
      int l = tid + (it << 8);
      int k = l >> 7, n = l & 127;
      Bs[n * LDT + k] = (short)f2b(Bg[(size_t)(k0 + k) * HW + n0 + n]);
    }
    __syncthreads();
    short8 af[4], bf[4];
    #pragma unroll
    for (int mi = 0; mi < 4; ++mi)
      af[mi] = *(const short8*)&As[(wm + (mi << 4) + l16) * LDT + (quad << 3)];
    #pragma unroll
    for (int ni = 0; ni < 4; ++ni)
      bf[ni] = *(const short8*)&Bs[(wn + (ni << 4) + l16) * LDT + (quad << 3)];
    #pragma unroll
    for (int mi = 0; mi < 4; ++mi)
      #pragma unroll
      for (int ni = 0; ni < 4; ++ni)
        acc[mi][ni] = __builtin_amdgcn_mfma_f32_16x16x32_bf16(af[mi], bf[ni], acc[mi][ni], 0, 0, 0);
    __syncthreads();
  }
  #pragma unroll
  for (int mi = 0; mi < 4; ++mi)
    #pragma unroll
    for (int reg = 0; reg < 4; ++reg) {
      int m = m0 + wm + (mi << 4) + (quad << 2) + reg;
      float bv = bias[m];
      size_t base = ((size_t)b * MID + m) * HW + n0 + wn + l16;
      #pragma unroll
      for (int ni = 0; ni < 4; ++ni)
        out[base + (ni << 4)] = acc[mi][ni][reg] + bv;
    }
}

// variant 2: B = bf16 rows scattered in fftf planes; +bias +residual
__global__ __launch_bounds__(256) void k_gemm_post(
    const unsigned short* __restrict__ A, const float* __restrict__ fftf,
    const float* __restrict__ bias, const float* __restrict__ x,
    float* __restrict__ y)
{
  __shared__ __align__(16) short As[128 * LDT];
  __shared__ __align__(16) short Bs[128 * LDT];
  const int tid = threadIdx.x;
  const int n0 = blockIdx.x << 7;
  const int m0 = blockIdx.y << 7;
  const int b  = blockIdx.z;
  const int lane = tid & 63, wave = tid >> 6;
  const int wm = (wave >> 1) << 6, wn = (wave & 1) << 6;
  const int l16 = lane & 15, quad = lane >> 4;
  floatx4 acc[4][4] = {};
  for (int k0 = 0; k0 < 2 * MID; k0 += 32) {
    #pragma unroll
    for (int l = tid; l < 512; l += 256) {
      int m = l >> 2, ko = (l & 3) << 3;
      *(uint4*)&As[m * LDT + ko] = *(const uint4*)&A[(size_t)(m0 + m) * (2 * MID) + k0 + ko];
    }
    #pragma unroll
    for (int it = 0; it < 16; ++it) {
      int l = tid + (it << 8);
      int k = l >> 7, n = l & 127;
      int cidx = k0 + k;
      const unsigned short* row = (const unsigned short*)
          (fftf + (size_t)(b * MID + (cidx & 255)) * (2 * HW) + ((cidx < MID) ? HW : 0));
      Bs[n * LDT + k] = (short)row[n0 + n];
    }
    __syncthreads();
    short8 af[4], bf[4];
    #pragma unroll
    for (int mi = 0; mi < 4; ++mi)
      af[mi] = *(const short8*)&As[(wm + (mi << 4) + l16) * LDT + (quad << 3)];
    #pragma unroll
    for (int ni = 0; ni < 4; ++ni)
      bf[ni] = *(const short8*)&Bs[(wn + (ni << 4) + l16) * LDT + (quad << 3)];
    #pragma unroll
    for (int mi = 0; mi < 4; ++mi)
      #pragma unroll
      for (int ni = 0; ni < 4; ++ni)
        acc[mi][ni] = __builtin_amdgcn_mfma_f32_16x16x32_bf16(af[mi], bf[ni], acc[mi][ni], 0, 0, 0);
    __syncthreads();
  }
  #pragma unroll
  for (int mi = 0; mi < 4; ++mi)
    #pragma unroll
    for (int reg = 0; reg < 4; ++reg) {
      int m = m0 + wm + (mi << 4) + (quad << 2) + reg;
      float bv = bias[m];
      size_t base = ((size_t)b * CIN + m) * HW + n0 + wn + l16;
      #pragma unroll
      for (int ni = 0; ni < 4; ++ni)
        y[base + (ni << 4)] = acc[mi][ni][reg] + bv + x[base + (ni << 4)];
    }
}

// ------------------------------------------------------------------ K2: depthwise 3x3 + BN + ReLU + spatial mean
__global__ __launch_bounds__(256) void k_dwbn(
    const float* __restrict__ in, const float* __restrict__ dww,
    const float* __restrict__ dwb, const float* __restrict__ gamma,
    const float* __restrict__ beta, const float* __restrict__ mean,
    const float* __restrict__ var, float* __restrict__ out,
    float* __restrict__ g0)
{
  __shared__ float pl[HW];
  __shared__ float red[256];
  const int p = blockIdx.x;
  const int c = p & (MID - 1);
  const int tid = threadIdx.x;
  const float* ip = in + (size_t)p * HW;
  for (int l = tid; l < HW; l += 256) pl[l] = ip[l];
  float wreg[9];
  #pragma unroll
  for (int i = 0; i < 9; ++i) wreg[i] = dww[c * 9 + i];
  const float bconv = dwb[c];
  const float inv = gamma[c] * rsqrtf(var[c] + 1e-5f);
  const float mu = mean[c], bt = beta[c];
  __syncthreads();
  float lsum = 0.f;
  float* op = out + (size_t)p * HW;
  for (int l = tid; l < HW; l += 256) {
    int y = l >> 6, xx0 = l & 63;
    float s = bconv;
    #pragma unroll
    for (int ky = 0; ky < 3; ++ky) {
      int yy = y + ky - 1;
      if (yy < 0 || yy >= 64) continue;
      #pragma unroll
      for (int kx = 0; kx < 3; ++kx) {
        int xx = xx0 + kx - 1;
        if (xx < 0 || xx >= 64) continue;
        s = fmaf(pl[(yy << 6) + xx], wreg[ky * 3 + kx], s);
      }
    }
    s = (s - mu) * inv + bt;
    s = fmaxf(s, 0.f);
    op[l] = s;
    lsum += s;
  }
  red[tid] = lsum;
  __syncthreads();
  for (int st = 128; st > 0; st >>= 1) {
    if (tid < st) red[tid] += red[tid + st];
    __syncthreads();
  }
  if (tid == 0) g0[p] = red[0] * (1.f / HW);
}

// ------------------------------------------------------------------ K3: SE gate MLP (tiny)
__global__ __launch_bounds__(256) void k_gate(
    const float* __restrict__ g0, const float* __restrict__ w1,
    const float* __restrict__ b1, const float* __restrict__ w2,
    const float* __restrict__ b2, float* __restrict__ g)
{
  __shared__ float gs[MID];
  __shared__ float hs[32];
  const int b = blockIdx.x;
  const int tid = threadIdx.x;
  gs[tid] = g0[b * MID + tid];
  __syncthreads();
  if (tid < 32) {
    float s = b1[tid];
    for (int c = 0; c < MID; ++c) s = fmaf(gs[c], w1[tid * MID + c], s);
    hs[tid] = fmaxf(s, 0.f);
  }
  __syncthreads();
  float s = b2[tid];
  #pragma unroll
  for (int j = 0; j < 32; ++j) s = fmaf(hs[j], w2[tid * 32 + j], s);
  g[b * MID + tid] = 1.f / (1.f + expf(-s));
}

// ------------------------------------------------------------------ K4: forward 2D DFT (ortho), real input -> complex out
__global__ __launch_bounds__(256) void k_fft_fwd(
    const float* __restrict__ in, float* __restrict__ outf)
{
  __shared__ float Ar[HW];
  __shared__ float Ai[HW];
  __shared__ float twc[64], tws[64];
  const int tid = threadIdx.x;
  const int p = blockIdx.x;
  if (tid < 64) {
    float ang = -PI2 * (float)tid * (1.f / 64.f);
    twc[tid] = cosf(ang);
    tws[tid] = sinf(ang);
  }
  const float* ip = in + (size_t)p * HW;
  for (int l = tid; l < HW; l += 256) Ar[l] = ip[l];
  __syncthreads();
  float orr[16], oii[16];
  #pragma unroll
  for (int ii = 0; ii < 16; ++ii) {
    int l = tid + (ii << 8);
    int r = l >> 6, k = l & 63;
    const float* row = Ar + (r << 6);
    float sr = 0.f, si = 0.f;
    for (int c = 0; c < 64; ++c) {
      int t = (c * k) & 63;
      float v = row[c];
      sr = fmaf(v, twc[t], sr);
      si = fmaf(v, tws[t], si);
    }
    orr[ii] = sr; oii[ii] = si;
  }
  __syncthreads();
  #pragma unroll
  for (int ii = 0; ii < 16; ++ii) {
    int l = tid + (ii << 8);
    Ar[l] = orr[ii]; Ai[l] = oii[ii];
  }
  __syncthreads();
  float2* op = (float2*)(outf + (size_t)p * (2 * HW));
  #pragma unroll
  for (int ii = 0; ii < 16; ++ii) {
    int l = tid + (ii << 8);
    int j = l >> 6, k = l & 63;
    float sr = 0.f, si = 0.f;
    for (int r = 0; r < 64; ++r) {
      int t = (r * j) & 63;
      float tc = twc[t], ts = tws[t];
      float ar = Ar[(r << 6) + k], ai = Ai[(r << 6) + k];
      sr += tc * ar - ts * ai;
      si += tc * ai + ts * ar;
    }
    op[l] = make_float2(sr * (1.f / 64.f), si * (1.f / 64.f));
  }
}

// ------------------------------------------------------------------ K5a: attention scores (partial over n-chunks)
__global__ __launch_bounds__(256) void k_attn_s(
    const float* __restrict__ fftf, float* __restrict__ Sbuf,
    float* __restrict__ Nbuf)
{
  const int bh = blockIdx.y;
  const int n0 = blockIdx.x << 8;
  const int b = bh >> 3, h = bh & 7;
  const float2* Q = (const float2*)fftf + ((size_t)b * MID + (size_t)h * CH) * HW;
  __shared__ float2 Lri[32 * 257];
  const int tid = threadIdx.x;
  for (int l = tid; l < 8192; l += 256) {
    int r = l >> 8, nn = l & 255;
    Lri[r * 257 + nn] = Q[(size_t)r * HW + n0 + nn];
  }
  __syncthreads();
  const int c0 = (tid >> 4) << 1;
  const int d0 = (tid & 15) << 1;
  const float2* ca = Lri + c0 * 257;
  const float2* cb = ca + 257;
  const float2* da = Lri + d0 * 257;
  const float2* db = da + 257;
  float s00 = 0.f, s01 = 0.f, s10 = 0.f, s11 = 0.f;
  for (int nn = 0; nn < 256; ++nn) {
    float2 A0 = ca[nn], A1 = cb[nn], B0 = da[nn], B1 = db[nn];
    s00 = fmaf(A0.x, B0.x, s00); s00 = fmaf(-A0.y, B0.y, s00);
    s01 = fmaf(A0.x, B1.x, s01); s01 = fmaf(-A0.y, B1.y, s01);
    s10 = fmaf(A1.x, B0.x, s10); s10 = fmaf(-A1.y, B0.y, s10);
    s11 = fmaf(A1.x, B1.x, s11); s11 = fmaf(-A1.y, B1.y, s11);
  }
  float* Sp = Sbuf + (size_t)bh * 1024;
  atomicAdd(&Sp[(c0    ) * 32 + d0    ], s00);
  atomicAdd(&Sp[(c0    ) * 32 + d0 + 1], s01);
  atomicAdd(&Sp[(c0 + 1) * 32 + d0    ], s10);
  atomicAdd(&Sp[(c0 + 1) * 32 + d0 + 1], s11);
  {
    int r = tid >> 3;
    const float2* rr = Lri + r * 257;
    float t = 0.f;
    for (int nn = tid & 7; nn < 256; nn += 8) {
      float2 v = rr[nn];
      t = fmaf(v.x, v.x, t);
      t = fmaf(v.y, v.y, t);
    }
    atomicAdd(&Nbuf[bh * 32 + r], t);
  }
}

// ------------------------------------------------------------------ K5b: normalize + temperature + softmax
__global__ __launch_bounds__(64) void k_attn_sm(
    float* __restrict__ Sbuf, const float* __restrict__ Nbuf,
    const float* __restrict__ temp)
{
  const int bh = blockIdx.x;
  const int h = bh & 7;
  const int tid = threadIdx.x;
  if (tid < 32) {
    float nc = fmaxf(sqrtf(Nbuf[bh * 32 + tid]), 1e-12f);
    float tmp = temp[h];
    float* Sp = Sbuf + (size_t)bh * 1024 + tid * 32;
    float vals[32];
    float vmax = -1e30f;
    #pragma unroll
    for (int d = 0; d < 32; ++d) {
      float nd = fmaxf(sqrtf(Nbuf[bh * 32 + d]), 1e-12f);
      float v = Sp[d] / (nc * nd) * tmp;
      vals[d] = v;
      vmax = fmaxf(vmax, v);
    }
    float sum = 0.f;
    #pragma unroll
    for (int d = 0; d < 32; ++d) {
      float e = expf(vals[d] - vmax);
      vals[d] = e;
      sum += e;
    }
    float rinv = 1.f / sum;
    #pragma unroll
    for (int d = 0; d < 32; ++d) Sp[d] = vals[d] * rinv;
  }
}

// ------------------------------------------------------------------ K5c: out[c,n] = sum_d P[c,d] * Re(Q[d,n])
__global__ __launch_bounds__(256) void k_attn_o(
    const float* __restrict__ fftf, const float* __restrict__ Sbuf,
    float* __restrict__ outw)
{
  const int bh = blockIdx.y;
  const int n0 = blockIdx.x << 9;
  const int b = bh >> 3, h = bh & 7;
  const float2* Q = (const float2*)fftf + ((size_t)b * MID + (size_t)h * CH) * HW;
  __shared__ float P[1024];
  __shared__ float Lr[32 * 514];
  const int tid = threadIdx.x;
  for (int l = tid; l < 1024; l += 256) P[l] = Sbuf[(size_t)bh * 1024 + l];
  for (int l = tid; l < 32 * 512; l += 256) {
    int r = l >> 9, nn = l & 511;
    Lr[r * 514 + nn] = Q[(size_t)r * HW + n0 + nn].x;
  }
  __syncthreads();
  const float2* Lr2 = (const float2*)Lr;
  const float4* P4 = (const float4*)P;
  float* orow = outw + ((size_t)b * MID + (size_t)h * CH) * HW + n0;
  #pragma unroll 4
  for (int c = 0; c < 32; ++c) {
    float s0 = 0.f, s1 = 0.f;
    #pragma unroll
    for (int j = 0; j < 8; ++j) {
      float4 pv = P4[c * 8 + j];
      int d = j << 2;
      float2 v0 = Lr2[(d + 0) * 257 + tid];
      float2 v1 = Lr2[(d + 1) * 257 + tid];
      float2 v2 = Lr2[(d + 2) * 257 + tid];
      float2 v3 = Lr2[(d + 3) * 257 + tid];
      s0 = fmaf(pv.x, v0.x, s0); s1 = fmaf(pv.x, v0.y, s1);
      s0 = fmaf(pv.y, v1.x, s0); s1 = fmaf(pv.y, v1.y, s1);
      s0 = fmaf(pv.z, v2.x, s0); s1 = fmaf(pv.z, v2.y, s1);
      s0 = fmaf(pv.w, v3.x, s0); s1 = fmaf(pv.w, v3.y, s1);
    }
    ((float2*)(orow + (size_t)c * HW))[tid] = make_float2(s0, s1);
  }
}

// ------------------------------------------------------------------ K6: attn inverse transform -> bf16 into plane bytes [16KB,24KB)
__global__ __launch_bounds__(256) void k_ifft_re(
    const float* __restrict__ in, float* __restrict__ fftf)
{
  __shared__ float Ar[HW];
  __shared__ float Ai[HW];
  __shared__ float twc[64], tws[64];
  const int tid = threadIdx.x;
  const int p = blockIdx.x;
  if (tid < 64) {
    float ang = -PI2 * (float)tid * (1.f / 64.f);
    twc[tid] = cosf(ang);
    tws[tid] = sinf(ang);
  }
  const float* ip = in + (size_t)p * HW;
  for (int l = tid; l < HW; l += 256) Ar[l] = ip[l];
  __syncthreads();
  float orr[16], oii[16];
  #pragma unroll
  for (int ii = 0; ii < 16; ++ii) {
    int l = tid + (ii << 8);
    int r = l >> 6, k = l & 63;
    const float* row = Ar + (r << 6);
    float sr = 0.f, si = 0.f;
    for (int c = 0; c < 64; ++c) {
      int t = (c * k) & 63;
      float v = row[c];
      sr = fmaf(v, twc[t], sr);
      si = fmaf(v, tws[t], si);
    }
    orr[ii] = sr; oii[ii] = si;
  }
  __syncthreads();
  #pragma unroll
  for (int ii = 0; ii < 16; ++ii) {
    int l = tid + (ii << 8);
    Ar[l] = orr[ii]; Ai[l] = oii[ii];
  }
  __syncthreads();
  unsigned short* op = (unsigned short*)(fftf + (size_t)p * (2 * HW) + HW);
  #pragma unroll
  for (int ii = 0; ii < 16; ++ii) {
    int l = tid + (ii << 8);
    int j = l >> 6, k = l & 63;
    float sr = 0.f;
    for (int r = 0; r < 64; ++r) {
      int t = (r * j) & 63;
      sr += twc[t] * Ar[(r << 6) + k] - tws[t] * Ai[(r << 6) + k];
    }
    op[l] = f2b(sr * (1.f / 64.f));
  }
}

// ------------------------------------------------------------------ K7: fwm -> bf16 into plane bytes [0,8KB)
__global__ __launch_bounds__(256) void k_fwm(
    float* __restrict__ fftf, const float* __restrict__ g)
{
  __shared__ float Zr[HW];
  __shared__ float Zi[HW];
  __shared__ float twc[64], tws[64];
  const int tid = threadIdx.x;
  const int p = blockIdx.x;
  if (tid < 64) {
    float ang = PI2 * (float)tid * (1.f / 64.f);
    twc[tid] = cosf(ang);
    tws[tid] = sinf(ang);
  }
  float* plane = fftf + (size_t)p * (2 * HW);
  const float2* F = (const float2*)plane;
  for (int l = tid; l < HW; l += 256) {
    float2 v = F[l];
    Zr[l] = v.x * v.x - v.y * v.y;
    Zi[l] = 2.f * v.x * v.y;
  }
  __syncthreads();
  float orr[16], oii[16];
  #pragma unroll
  for (int ii = 0; ii < 16; ++ii) {
    int l = tid + (ii << 8);
    int r = l >> 6, n = l & 63;
    const float* zr = Zr + (r << 6);
    const float* zi = Zi + (r << 6);
    float sr = 0.f, si = 0.f;
    for (int k = 0; k < 64; ++k) {
      int t = (k * n) & 63;
      float tc = twc[t], ts = tws[t];
      float ar = zr[k], ai = zi[k];
      sr += ar * tc - ai * ts;
      si += ar * ts + ai * tc;
    }
    orr[ii] = sr; oii[ii] = si;
  }
  __syncthreads();
  #pragma unroll
  for (int ii = 0; ii < 16; ++ii) {
    int l = tid + (ii << 8);
    Zr[l] = orr[ii]; Zi[l] = oii[ii];
  }
  __syncthreads();
  const float gg = g[p] * (1.f / 64.f);
  unsigned short* ob = (unsigned short*)plane;
  #pragma unroll
  for (int ii = 0; ii < 16; ++ii) {
    int l = tid + (ii << 8);
    int m = l >> 6, n = l & 63;
    float sr = 0.f;
    for (int j = 0; j < 64; ++j) {
      int t = (j * m) & 63;
      sr += twc[t] * Zr[(j << 6) + n] - tws[t] * Zi[(j << 6) + n];
    }
    ob[l] = f2b(sr * gg);
  }
}

// ------------------------------------------------------------------ launch
extern "C" void kernel_launch(void* const* d_in, const int* in_sizes, int n_in,
                              void* d_out, int out_size, void* d_ws, size_t ws_size,
                              hipStream_t stream)
{
  const float* x    = (const float*)d_in[0];
  const float* rw   = (const float*)d_in[1];
  const float* rb   = (const float*)d_in[2];
  const float* dww  = (const float*)d_in[3];
  const float* dwb  = (const float*)d_in[4];
  const float* bng  = (const float*)d_in[5];
  const float* bnb  = (const float*)d_in[6];
  const float* bnm  = (const float*)d_in[7];
  const float* bnv  = (const float*)d_in[8];
  const float* gw1  = (const float*)d_in[9];
  const float* gb1  = (const float*)d_in[10];
  const float* gw2  = (const float*)d_in[11];
  const float* gb2  = (const float*)d_in[12];
  const float* temp = (const float*)d_in[13];
  const float* pw   = (const float*)d_in[14];
  const float* pb   = (const float*)d_in[15];
  float* y = (float*)d_out;

  float* ws = (float*)d_ws;
  const size_t PL = (size_t)BATCH * MID * HW;
  float* xr   = ws;                       // dwbn out (fp32)
  float* fftf = ws + PL;                  // complex planes; later bf16 fwm/osp
  float* g0   = ws + 3 * PL;
  float* gg   = g0 + BATCH * MID;
  float* Sbuf = gg + BATCH * MID;
  float* Nbuf = Sbuf + BATCH * HEADS * 1024;
  unsigned short* rwB = (unsigned short*)(Nbuf + BATCH * HEADS * 32);
  unsigned short* pwB = rwB + MID * CIN;
  float* xr0  = y;                        // d_out as scratch: reduce out, then attn out

  hipMemsetAsync(Sbuf, 0, (size_t)(BATCH * HEADS * (1024 + 32)) * sizeof(float), stream);

  k_castw    <<<dim3(1024),            256, 0, stream>>>(rw, pw, rwB, pwB);
  k_gemm_red <<<dim3(32, 2, BATCH),    256, 0, stream>>>(rwB, x, rb, xr0);
  k_dwbn     <<<dim3(BATCH * MID),     256, 0, stream>>>(xr0, dww, dwb, bng, bnb, bnm, bnv, xr, g0);
  k_gate     <<<dim3(BATCH),           256, 0, stream>>>(g0, gw1, gb1, gw2, gb2, gg);
  k_fft_fwd  <<<dim3(BATCH * MID),     256, 0, stream>>>(xr, fftf);
  k_attn_s   <<<dim3(16, BATCH * HEADS), 256, 0, stream>>>(fftf, Sbuf, Nbuf);
  k_attn_sm  <<<dim3(BATCH * HEADS),   64,  0, stream>>>(Sbuf, Nbuf, temp);
  k_attn_o   <<<dim3(8, BATCH * HEADS), 256, 0, stream>>>(fftf, Sbuf, xr0);
  k_fwm      <<<dim3(BATCH * MID),     256, 0, stream>>>(fftf, gg);
  k_ifft_re  <<<dim3(BATCH * MID),     256, 0, stream>>>(xr0, fftf);
  k_gemm_post<<<dim3(32, 4, BATCH),    256, 0, stream>>>(pwB, fftf, pb, x, y);
}